// Round 1
// baseline (596.517 us; speedup 1.0000x reference)
//
#include <hip/hip_runtime.h>
#include <math.h>

#define B_ 16
#define L_ 512
#define D_ 768
#define H_ 12
#define K_ 128
#define U_ 256
#define NH_ 4
#define HD_ 64
#define OUTROWS_ 130   // 1 class + 128 preserved + 1 new

// ---------------------------------------------------------------------------
// Kernel 1: importance[b,l] = (1/H) * sum_{h,q} scores[b,h,q,l]
// scores layout [B][H][L][L], l contiguous -> fully coalesced.
// Grid (48 chunks, B), block 512 (one thread per l). 48*128 = 6144 = H*L rows.
// ---------------------------------------------------------------------------
__global__ __launch_bounds__(512) void importance_kernel(
    const float* __restrict__ scores, float* __restrict__ imp) {
  const int b = blockIdx.y;
  const int chunk = blockIdx.x;
  const int t = threadIdx.x;  // l
  const float* base = scores + ((size_t)b * (H_ * L_) + (size_t)chunk * 128) * L_ + t;
  float a0 = 0.f, a1 = 0.f, a2 = 0.f, a3 = 0.f;
  #pragma unroll 8
  for (int r = 0; r < 128; r += 4) {
    a0 += base[(size_t)(r + 0) * L_];
    a1 += base[(size_t)(r + 1) * L_];
    a2 += base[(size_t)(r + 2) * L_];
    a3 += base[(size_t)(r + 3) * L_];
  }
  atomicAdd(&imp[b * L_ + t], (a0 + a1 + a2 + a3) * (1.0f / 12.0f));
}

// ---------------------------------------------------------------------------
// Kernel 2: top-K=128 per batch via rank counting; writes sorted indices and
// the final_attention_mask output (out1). One block of 512 per batch.
// ---------------------------------------------------------------------------
__global__ __launch_bounds__(512) void topk_kernel(
    const float* __restrict__ imp, const float* __restrict__ mask,
    int* __restrict__ idx, float* __restrict__ out1) {
  __shared__ float v[L_];
  __shared__ int sel[L_];
  const int b = blockIdx.x, t = threadIdx.x;
  v[t] = imp[b * L_ + t];
  __syncthreads();
  const float mv = v[t];
  int cnt = 0;
  #pragma unroll 8
  for (int j = 0; j < L_; ++j) {
    float o = v[j];
    cnt += (o > mv) || (o == mv && j < t);  // stable tie-break like lax.top_k
  }
  sel[t] = (cnt < K_) ? 1 : 0;
  __syncthreads();
  if (sel[t]) {
    int pos = 0;
    for (int j = 0; j < t; ++j) pos += sel[j];
    idx[b * K_ + pos] = t;
    out1[b * OUTROWS_ + 1 + pos] = mask[b * L_ + t];
  }
  if (t == 0) {
    out1[b * OUTROWS_ + 0] = 0.f;
    out1[b * OUTROWS_ + OUTROWS_ - 1] = 0.f;
  }
}

// ---------------------------------------------------------------------------
// Block reduction helpers (block = 768 threads = 12 waves of 64)
// ---------------------------------------------------------------------------
__device__ __forceinline__ float blk_max768(float v, float* red, int t) {
  __syncthreads();
  #pragma unroll
  for (int o = 32; o > 0; o >>= 1) v = fmaxf(v, __shfl_down(v, o, 64));
  if ((t & 63) == 0) red[t >> 6] = v;
  __syncthreads();
  if (t == 0) {
    float r = red[0];
    #pragma unroll
    for (int w = 1; w < 12; ++w) r = fmaxf(r, red[w]);
    red[0] = r;
  }
  __syncthreads();
  return red[0];
}

__device__ __forceinline__ float blk_sum768(float v, float* red, int t) {
  __syncthreads();
  #pragma unroll
  for (int o = 32; o > 0; o >>= 1) v += __shfl_down(v, o, 64);
  if ((t & 63) == 0) red[t >> 6] = v;
  __syncthreads();
  if (t == 0) {
    float r = 0.f;
    #pragma unroll
    for (int w = 0; w < 12; ++w) r += red[w];
    red[0] = r;
  }
  __syncthreads();
  return red[0];
}

// ---------------------------------------------------------------------------
// Kernel 3: the whole attention path for one batch per block (768 threads).
// mask-softmax -> sentences -> q -> folded-q key proj -> scores -> softmax
// -> ctx -> out -> new_token (written directly to out0 row 129).
// Key algebraic collapse: never materialize k/v (B,L,U). Instead:
//   scores[h,l] = sum_d hidden[l,d] * wq_eff[h,d],
//     wq_eff[h,d] = sum_{u in head h} q[u]*Wk[u,d]
//   out[u] = sum_d ctx[h(u),d] * Wv[u,d],
//     ctx[h,d] = sum_l probs[h,l]*hidden[l,d]
// ---------------------------------------------------------------------------
__global__ __launch_bounds__(768) void attn_kernel(
    const float* __restrict__ hidden, const float* __restrict__ mask,
    const float* __restrict__ Wq, const float* __restrict__ Wk,
    const float* __restrict__ Wv, const float* __restrict__ Wo,
    const float* __restrict__ bo, float* __restrict__ out0) {
  __shared__ float att[L_];
  __shared__ float mrow[L_];
  __shared__ float sent[D_];
  __shared__ float qv[U_];
  __shared__ float wq[NH_][D_];
  __shared__ float sc[NH_][L_];
  __shared__ float ctx[NH_][D_];
  __shared__ float outv[U_];
  __shared__ float red[16];

  const int b = blockIdx.x, t = threadIdx.x;
  const float* hb = hidden + (size_t)b * L_ * D_;

  // ---- phase 0: softmax over attention_mask row -> att[l]
  if (t < L_) mrow[t] = mask[b * L_ + t];
  __syncthreads();
  float m = (t < L_) ? mrow[t] : -INFINITY;
  float mx = blk_max768(m, red, t);
  float e = (t < L_) ? expf(m - mx) : 0.f;
  float se = blk_sum768(e, red, t);
  if (t < L_) att[t] = e / se;
  __syncthreads();

  // ---- phase 1: sentences[d] = sum_l att[l]*hidden[l,d]   (d = t, coalesced)
  {
    float acc = 0.f;
    const float* hp = hb + t;
    #pragma unroll 4
    for (int l = 0; l < L_; ++l) acc += att[l] * hp[(size_t)l * D_];
    sent[t] = acc;
  }
  __syncthreads();

  // ---- phase 2: q[u] = sum_d sent[d]*Wq[u,d]
  if (t < U_) {
    const float* wr = Wq + (size_t)t * D_;
    float acc = 0.f;
    #pragma unroll 4
    for (int d = 0; d < D_; ++d) acc += sent[d] * wr[d];
    qv[t] = acc;
  }
  __syncthreads();

  // ---- phase 3: wq_eff[h][d] = sum_{j<64} q[64h+j]*Wk[64h+j, d]  (h=j-loop, d=t)
  #pragma unroll
  for (int h = 0; h < NH_; ++h) {
    float acc = 0.f;
    const float* wk = Wk + (size_t)(h * HD_) * D_ + t;
    #pragma unroll 4
    for (int j = 0; j < HD_; ++j) acc += qv[h * HD_ + j] * wk[(size_t)j * D_];
    wq[h][t] = acc;
  }
  __syncthreads();

  // ---- phase 4: scores[h][l] for l = t
  if (t < L_) {
    const float* hr = hb + (size_t)t * D_;
    float s0 = 0.f, s1 = 0.f, s2 = 0.f, s3 = 0.f;
    #pragma unroll 4
    for (int d = 0; d < D_; ++d) {
      float hv = hr[d];
      s0 += hv * wq[0][d];
      s1 += hv * wq[1][d];
      s2 += hv * wq[2][d];
      s3 += hv * wq[3][d];
    }
    const float scale = 0.03608439182435161f;  // 1/sqrt(768)
    const bool kp = mrow[t] < -10.f;
    sc[0][t] = kp ? -INFINITY : s0 * scale;
    sc[1][t] = kp ? -INFINITY : s1 * scale;
    sc[2][t] = kp ? -INFINITY : s2 * scale;
    sc[3][t] = kp ? -INFINITY : s3 * scale;
  }
  __syncthreads();

  // ---- phase 5: softmax over l per head
  for (int h = 0; h < NH_; ++h) {
    float v = (t < L_) ? sc[h][t] : -INFINITY;
    float hmx = blk_max768(v, red, t);
    float he = (t < L_) ? expf(v - hmx) : 0.f;
    float hs = blk_sum768(he, red, t);
    if (t < L_) sc[h][t] = he / hs;
    __syncthreads();
  }

  // ---- phase 6: ctx[h][d] = sum_l probs[h][l]*hidden[l,d]  (d = t, coalesced)
  {
    float c0 = 0.f, c1 = 0.f, c2 = 0.f, c3 = 0.f;
    const float* hp = hb + t;
    #pragma unroll 4
    for (int l = 0; l < L_; ++l) {
      float hv = hp[(size_t)l * D_];
      c0 += sc[0][l] * hv;
      c1 += sc[1][l] * hv;
      c2 += sc[2][l] * hv;
      c3 += sc[3][l] * hv;
    }
    ctx[0][t] = c0; ctx[1][t] = c1; ctx[2][t] = c2; ctx[3][t] = c3;
  }
  __syncthreads();

  // ---- phase 7: out[u] = sum_d ctx[h(u)][d]*Wv[u,d]
  if (t < U_) {
    const int h = t >> 6;
    const float* wv = Wv + (size_t)t * D_;
    float acc = 0.f;
    #pragma unroll 4
    for (int d = 0; d < D_; ++d) acc += ctx[h][d] * wv[d];
    outv[t] = acc;
  }
  __syncthreads();

  // ---- phase 8: new_token[d] = bo[d] + sum_u out[u]*Wo[d,u]  (d = t)
  {
    const float* wo = Wo + (size_t)t * U_;
    float acc = bo[t];
    #pragma unroll 4
    for (int u = 0; u < U_; ++u) acc += outv[u] * wo[u];
    out0[((size_t)b * OUTROWS_ + (OUTROWS_ - 1)) * D_ + t] = acc;
  }
}

// ---------------------------------------------------------------------------
// Kernel 4: gather class token (row 0) + preserved tokens (rows 1..128).
// One block per output row, float4 copies (768 floats = 192 lanes).
// ---------------------------------------------------------------------------
__global__ __launch_bounds__(192) void gather_kernel(
    const float* __restrict__ hidden, const int* __restrict__ idx,
    float* __restrict__ out0) {
  const int b = blockIdx.y;
  const int r = blockIdx.x;  // 0..128
  const int src_l = (r == 0) ? 0 : idx[b * K_ + (r - 1)];
  const float4* s = (const float4*)(hidden + ((size_t)b * L_ + src_l) * D_);
  float4* d = (float4*)(out0 + ((size_t)b * OUTROWS_ + r) * D_);
  d[threadIdx.x] = s[threadIdx.x];
}

extern "C" void kernel_launch(void* const* d_in, const int* in_sizes, int n_in,
                              void* d_out, int out_size, void* d_ws, size_t ws_size,
                              hipStream_t stream) {
  const float* hidden = (const float*)d_in[0];
  const float* mask   = (const float*)d_in[1];
  const float* sas    = (const float*)d_in[2];
  const float* Wq     = (const float*)d_in[3];
  const float* Wk     = (const float*)d_in[4];
  const float* Wv     = (const float*)d_in[5];
  const float* Wo     = (const float*)d_in[6];
  const float* bo     = (const float*)d_in[7];

  float* out0 = (float*)d_out;                       // (B,130,D)
  float* out1 = out0 + (size_t)B_ * OUTROWS_ * D_;   // (B,1,1,130)

  float* imp = (float*)d_ws;            // B*L floats
  int* idx = (int*)(imp + B_ * L_);     // B*K ints

  hipMemsetAsync(imp, 0, (size_t)B_ * L_ * sizeof(float), stream);
  importance_kernel<<<dim3(48, B_), 512, 0, stream>>>(sas, imp);
  topk_kernel<<<B_, 512, 0, stream>>>(imp, mask, idx, out1);
  attn_kernel<<<B_, 768, 0, stream>>>(hidden, mask, Wq, Wk, Wv, Wo, bo, out0);
  gather_kernel<<<dim3(OUTROWS_ - 1, B_), 192, 0, stream>>>(hidden, idx, out0);
}

// Round 2
// 482.842 us; speedup vs baseline: 1.2354x; 1.2354x over previous
//
#include <hip/hip_runtime.h>
#include <math.h>

#define B_ 16
#define L_ 512
#define D_ 768
#define H_ 12
#define K_ 128
#define U_ 256
#define NH_ 4
#define HD_ 64
#define OUTROWS_ 130   // 1 class + 128 preserved + 1 new

// ---------------------------------------------------------------------------
// Block reduction helpers. 768-thread (12 wave) and 512-thread (8 wave).
// ---------------------------------------------------------------------------
__device__ __forceinline__ float blk_max768(float v, float* red, int t) {
  __syncthreads();
  #pragma unroll
  for (int o = 32; o > 0; o >>= 1) v = fmaxf(v, __shfl_down(v, o, 64));
  if ((t & 63) == 0) red[t >> 6] = v;
  __syncthreads();
  if (t == 0) {
    float r = red[0];
    #pragma unroll
    for (int w = 1; w < 12; ++w) r = fmaxf(r, red[w]);
    red[0] = r;
  }
  __syncthreads();
  return red[0];
}

__device__ __forceinline__ float blk_sum768(float v, float* red, int t) {
  __syncthreads();
  #pragma unroll
  for (int o = 32; o > 0; o >>= 1) v += __shfl_down(v, o, 64);
  if ((t & 63) == 0) red[t >> 6] = v;
  __syncthreads();
  if (t == 0) {
    float r = 0.f;
    #pragma unroll
    for (int w = 0; w < 12; ++w) r += red[w];
    red[0] = r;
  }
  __syncthreads();
  return red[0];
}

__device__ __forceinline__ float blk_max512(float v, float* red, int t) {
  __syncthreads();
  #pragma unroll
  for (int o = 32; o > 0; o >>= 1) v = fmaxf(v, __shfl_down(v, o, 64));
  if ((t & 63) == 0) red[t >> 6] = v;
  __syncthreads();
  if (t == 0) {
    float r = red[0];
    #pragma unroll
    for (int w = 1; w < 8; ++w) r = fmaxf(r, red[w]);
    red[0] = r;
  }
  __syncthreads();
  return red[0];
}

__device__ __forceinline__ float blk_sum512(float v, float* red, int t) {
  __syncthreads();
  #pragma unroll
  for (int o = 32; o > 0; o >>= 1) v += __shfl_down(v, o, 64);
  if ((t & 63) == 0) red[t >> 6] = v;
  __syncthreads();
  if (t == 0) {
    float r = 0.f;
    #pragma unroll
    for (int w = 0; w < 8; ++w) r += red[w];
    red[0] = r;
  }
  __syncthreads();
  return red[0];
}

// ---------------------------------------------------------------------------
// importance[b,l] = (1/H) * sum_{h,q} scores[b,h,q,l]
// Grid (48, B), block 512 (t = l, coalesced). 48 chunks x 128 rows = H*L rows.
// ---------------------------------------------------------------------------
__global__ __launch_bounds__(512) void importance_kernel(
    const float* __restrict__ scores, float* __restrict__ imp) {
  const int b = blockIdx.y;
  const int chunk = blockIdx.x;
  const int t = threadIdx.x;
  const float* base = scores + ((size_t)b * (H_ * L_) + (size_t)chunk * 128) * L_ + t;
  float a0 = 0.f, a1 = 0.f, a2 = 0.f, a3 = 0.f;
  #pragma unroll 8
  for (int r = 0; r < 128; r += 4) {
    a0 += base[(size_t)(r + 0) * L_];
    a1 += base[(size_t)(r + 1) * L_];
    a2 += base[(size_t)(r + 2) * L_];
    a3 += base[(size_t)(r + 3) * L_];
  }
  atomicAdd(&imp[b * L_ + t], (a0 + a1 + a2 + a3) * (1.0f / 12.0f));
}

// ---------------------------------------------------------------------------
// Top-K=128 per batch via rank counting; writes sorted idx + out1 mask row.
// ---------------------------------------------------------------------------
__global__ __launch_bounds__(512) void topk_kernel(
    const float* __restrict__ imp, const float* __restrict__ mask,
    int* __restrict__ idx, float* __restrict__ out1) {
  __shared__ float v[L_];
  __shared__ int sel[L_];
  const int b = blockIdx.x, t = threadIdx.x;
  v[t] = imp[b * L_ + t];
  __syncthreads();
  const float mv = v[t];
  int cnt = 0;
  #pragma unroll 8
  for (int j = 0; j < L_; ++j) {
    float o = v[j];
    cnt += (o > mv) || (o == mv && j < t);  // stable tie-break like lax.top_k
  }
  sel[t] = (cnt < K_) ? 1 : 0;
  __syncthreads();
  if (sel[t]) {
    int pos = 0;
    for (int j = 0; j < t; ++j) pos += sel[j];
    idx[b * K_ + pos] = t;
    out1[b * OUTROWS_ + 1 + pos] = mask[b * L_ + t];
  }
  if (t == 0) {
    out1[b * OUTROWS_ + 0] = 0.f;
    out1[b * OUTROWS_ + OUTROWS_ - 1] = 0.f;
  }
}

// ---------------------------------------------------------------------------
// sentences[b,d] = sum_l softmax(mask)[l] * hidden[b,l,d]
// Grid (B, 16): each block handles 32 l's for all 768 d's (t = d, coalesced),
// recomputing the mask softmax locally (2 KB read), atomicAdd partials.
// ---------------------------------------------------------------------------
__global__ __launch_bounds__(768) void sent_kernel(
    const float* __restrict__ hidden, const float* __restrict__ mask,
    float* __restrict__ sent) {
  __shared__ float att[L_];
  __shared__ float red[16];
  const int b = blockIdx.x, chunk = blockIdx.y, t = threadIdx.x;
  float m = (t < L_) ? mask[b * L_ + t] : -INFINITY;
  float mx = blk_max768(m, red, t);
  float e = (t < L_) ? expf(m - mx) : 0.f;
  float se = blk_sum768(e, red, t);
  if (t < L_) att[t] = e / se;
  __syncthreads();
  const int l0 = chunk * 32;
  const float* hp = hidden + ((size_t)b * L_ + l0) * D_ + t;
  float acc = 0.f;
  #pragma unroll 8
  for (int l = 0; l < 32; ++l) acc += att[l0 + l] * hp[(size_t)l * D_];
  atomicAdd(&sent[b * D_ + t], acc);
}

// ---------------------------------------------------------------------------
// q[u] = sent . Wq[u,:]; wq_eff[h,d] = sum_{j<64} q[64h+j] * Wk[64h+j, d]
// Grid B, block 768.
// ---------------------------------------------------------------------------
__global__ __launch_bounds__(768) void qproj_kernel(
    const float* __restrict__ sent, const float* __restrict__ Wq,
    const float* __restrict__ Wk, float* __restrict__ wqe) {
  __shared__ float s[D_];
  __shared__ float qv[U_];
  const int b = blockIdx.x, t = threadIdx.x;
  s[t] = sent[b * D_ + t];
  __syncthreads();
  if (t < U_) {
    const float* wr = Wq + (size_t)t * D_;
    float acc = 0.f;
    #pragma unroll 4
    for (int d = 0; d < D_; ++d) acc += s[d] * wr[d];
    qv[t] = acc;
  }
  __syncthreads();
  #pragma unroll
  for (int h = 0; h < NH_; ++h) {
    float acc = 0.f;
    const float* wk = Wk + (size_t)(h * HD_) * D_ + t;
    #pragma unroll 4
    for (int j = 0; j < HD_; ++j) acc += qv[h * HD_ + j] * wk[(size_t)j * D_];
    wqe[((size_t)b * NH_ + h) * D_ + t] = acc;
  }
}

// ---------------------------------------------------------------------------
// scores[b,h,l] = (hidden[b,l,:] . wq_eff[b,h,:]) / sqrt(D), masked.
// Grid (B, 16), block 256 (4 waves); wave handles 8 rows, lane reduces over d.
// ---------------------------------------------------------------------------
__global__ __launch_bounds__(256) void score_kernel(
    const float* __restrict__ hidden, const float* __restrict__ mask,
    const float* __restrict__ wqe, float* __restrict__ scores) {
  __shared__ float wq[NH_ * D_];
  const int b = blockIdx.x, chunk = blockIdx.y, t = threadIdx.x;
  for (int i = t; i < NH_ * D_; i += 256) wq[i] = wqe[(size_t)b * NH_ * D_ + i];
  __syncthreads();
  const int wave = t >> 6, lane = t & 63;
  const float scale = 0.03608439182435161f;  // 1/sqrt(768)
  #pragma unroll
  for (int r = 0; r < 8; ++r) {
    const int l = chunk * 32 + wave * 8 + r;
    const float* hr = hidden + ((size_t)b * L_ + l) * D_;
    float s0 = 0.f, s1 = 0.f, s2 = 0.f, s3 = 0.f;
    #pragma unroll
    for (int j = 0; j < 12; ++j) {
      const int d = lane + 64 * j;
      float hv = hr[d];
      s0 += hv * wq[0 * D_ + d];
      s1 += hv * wq[1 * D_ + d];
      s2 += hv * wq[2 * D_ + d];
      s3 += hv * wq[3 * D_ + d];
    }
    #pragma unroll
    for (int o = 32; o > 0; o >>= 1) {
      s0 += __shfl_down(s0, o, 64);
      s1 += __shfl_down(s1, o, 64);
      s2 += __shfl_down(s2, o, 64);
      s3 += __shfl_down(s3, o, 64);
    }
    if (lane == 0) {
      const bool kp = mask[b * L_ + l] < -10.f;
      float* sp = scores + (size_t)b * NH_ * L_ + l;
      sp[0 * L_] = kp ? -INFINITY : s0 * scale;
      sp[1 * L_] = kp ? -INFINITY : s1 * scale;
      sp[2 * L_] = kp ? -INFINITY : s2 * scale;
      sp[3 * L_] = kp ? -INFINITY : s3 * scale;
    }
  }
}

// ---------------------------------------------------------------------------
// In-place softmax over l per (b,h). Grid (B, NH), block 512.
// ---------------------------------------------------------------------------
__global__ __launch_bounds__(512) void prob_kernel(float* __restrict__ scores) {
  __shared__ float red[8];
  const int b = blockIdx.x, h = blockIdx.y, t = threadIdx.x;
  float* sp = scores + ((size_t)b * NH_ + h) * L_;
  float v = sp[t];
  float mx = blk_max512(v, red, t);
  float e = expf(v - mx);
  float se = blk_sum512(e, red, t);
  sp[t] = e / se;
}

// ---------------------------------------------------------------------------
// ctx[b,h,d] = sum_l probs[b,h,l] * hidden[b,l,d]
// Grid (B, 16): 32 l's per block, t = d (coalesced), atomicAdd partials.
// ---------------------------------------------------------------------------
__global__ __launch_bounds__(768) void ctx_kernel(
    const float* __restrict__ hidden, const float* __restrict__ probs,
    float* __restrict__ ctx) {
  __shared__ float pr[NH_][32];
  const int b = blockIdx.x, chunk = blockIdx.y, t = threadIdx.x;
  const int l0 = chunk * 32;
  if (t < NH_ * 32) pr[t >> 5][t & 31] = probs[((size_t)b * NH_ + (t >> 5)) * L_ + l0 + (t & 31)];
  __syncthreads();
  const float* hp = hidden + ((size_t)b * L_ + l0) * D_ + t;
  float c0 = 0.f, c1 = 0.f, c2 = 0.f, c3 = 0.f;
  #pragma unroll 8
  for (int l = 0; l < 32; ++l) {
    float hv = hp[(size_t)l * D_];
    c0 += pr[0][l] * hv;
    c1 += pr[1][l] * hv;
    c2 += pr[2][l] * hv;
    c3 += pr[3][l] * hv;
  }
  float* cb = ctx + (size_t)b * NH_ * D_ + t;
  atomicAdd(cb + 0 * D_, c0);
  atomicAdd(cb + 1 * D_, c1);
  atomicAdd(cb + 2 * D_, c2);
  atomicAdd(cb + 3 * D_, c3);
}

// ---------------------------------------------------------------------------
// out[u] = ctx[h(u),:] . Wv[u,:]; new_token[d] = bo[d] + sum_u out[u]*Wo[d,u]
// Grid B, block 768. Writes out0 row 129 directly.
// ---------------------------------------------------------------------------
__global__ __launch_bounds__(768) void out_kernel(
    const float* __restrict__ ctx, const float* __restrict__ Wv,
    const float* __restrict__ Wo, const float* __restrict__ bo,
    float* __restrict__ out0) {
  __shared__ float cs[NH_ * D_];
  __shared__ float outv[U_];
  const int b = blockIdx.x, t = threadIdx.x;
  for (int i = t; i < NH_ * D_; i += 768) cs[i] = ctx[(size_t)b * NH_ * D_ + i];
  __syncthreads();
  if (t < U_) {
    const int h = t >> 6;
    const float* wv = Wv + (size_t)t * D_;
    float acc = 0.f;
    #pragma unroll 4
    for (int d = 0; d < D_; ++d) acc += cs[h * D_ + d] * wv[d];
    outv[t] = acc;
  }
  __syncthreads();
  const float* wo = Wo + (size_t)t * U_;
  float acc = bo[t];
  #pragma unroll 4
  for (int u = 0; u < U_; ++u) acc += outv[u] * wo[u];
  out0[((size_t)b * OUTROWS_ + (OUTROWS_ - 1)) * D_ + t] = acc;
}

// ---------------------------------------------------------------------------
// Gather class token (row 0) + preserved tokens (rows 1..128), float4 copies.
// ---------------------------------------------------------------------------
__global__ __launch_bounds__(192) void gather_kernel(
    const float* __restrict__ hidden, const int* __restrict__ idx,
    float* __restrict__ out0) {
  const int b = blockIdx.y;
  const int r = blockIdx.x;  // 0..128
  const int src_l = (r == 0) ? 0 : idx[b * K_ + (r - 1)];
  const float4* s = (const float4*)(hidden + ((size_t)b * L_ + src_l) * D_);
  float4* d = (float4*)(out0 + ((size_t)b * OUTROWS_ + r) * D_);
  d[threadIdx.x] = s[threadIdx.x];
}

extern "C" void kernel_launch(void* const* d_in, const int* in_sizes, int n_in,
                              void* d_out, int out_size, void* d_ws, size_t ws_size,
                              hipStream_t stream) {
  const float* hidden = (const float*)d_in[0];
  const float* mask   = (const float*)d_in[1];
  const float* sas    = (const float*)d_in[2];
  const float* Wq     = (const float*)d_in[3];
  const float* Wk     = (const float*)d_in[4];
  const float* Wv     = (const float*)d_in[5];
  const float* Wo     = (const float*)d_in[6];
  const float* bo     = (const float*)d_in[7];

  float* out0 = (float*)d_out;                       // (B,130,D)
  float* out1 = out0 + (size_t)B_ * OUTROWS_ * D_;   // (B,1,1,130)

  // Workspace layout (floats). imp/sent/ctx are atomic targets -> zeroed.
  float* imp    = (float*)d_ws;                 // B*L     =  8192
  float* sent   = imp + B_ * L_;                // B*D     = 12288
  float* ctx    = sent + B_ * D_;               // B*NH*D  = 49152
  float* wqe    = ctx + B_ * NH_ * D_;          // B*NH*D  = 49152
  float* scores = wqe + B_ * NH_ * D_;          // B*NH*L  = 32768
  int*   idx    = (int*)(scores + B_ * NH_ * L_); // B*K   =  2048 ints

  hipMemsetAsync(d_ws, 0,
                 (size_t)(B_ * L_ + B_ * D_ + B_ * NH_ * D_) * sizeof(float),
                 stream);

  importance_kernel<<<dim3(48, B_), 512, 0, stream>>>(sas, imp);
  topk_kernel<<<B_, 512, 0, stream>>>(imp, mask, idx, out1);
  sent_kernel<<<dim3(B_, 16), 768, 0, stream>>>(hidden, mask, sent);
  qproj_kernel<<<B_, 768, 0, stream>>>(sent, Wq, Wk, wqe);
  score_kernel<<<dim3(B_, 16), 256, 0, stream>>>(hidden, mask, wqe, scores);
  prob_kernel<<<dim3(B_, NH_), 512, 0, stream>>>(scores);
  ctx_kernel<<<dim3(B_, 16), 768, 0, stream>>>(hidden, scores, ctx);
  out_kernel<<<B_, 768, 0, stream>>>(ctx, Wv, Wo, bo, out0);
  gather_kernel<<<dim3(OUTROWS_ - 1, B_), 192, 0, stream>>>(hidden, idx, out0);
}